// Round 15
// baseline (233.029 us; speedup 1.0000x reference)
//
#include <hip/hip_runtime.h>

// GraphSAGE encoder on MI355X — pipeline (r12 base + r15 interleaved agg):
//   memset(bcnt) ; k_work (bucket + prep in one launch) ; k_csr
//   k_layer1 (bf16-agg64 + dense1 fused; 4 nodes' gathers INTERLEAVED per
//             wave -> one drain point instead of 4, 4x gather MLP)
//   k_agg_u8 (layer-2 aggregation from u8 h1: 1 line/row — the r12 win)
//   k_dense23 (dense2+out fused, h2 in LDS; self-terms read full-prec pairs)
// r13 lesson: u8 quant only pays when it halves LINE REQUESTS, not bytes.
// Dense: split-bf16 MFMA (A@B ~= Ah@Bh + Al@Bh + Ah@Bl, fp32-equivalent).

typedef unsigned short ushort_t;
typedef unsigned int uint_t;
typedef unsigned char uchar_t;
typedef __attribute__((ext_vector_type(8))) short short8;
typedef __attribute__((ext_vector_type(8))) ushort_t ushort8;
typedef __attribute__((ext_vector_type(4))) float f32x4;

#define BKT_SHIFT 7
#define BKT_NODES 128
#define BKT_CAP   5120
#define EPB       4096
#define QSCALE    32.0f          // h1q = round(h1 * 32), u8 (post-relu >= 0)
#define QINV      0.03125f

__device__ inline ushort_t bf16_rne(float v) {
    uint_t u = __float_as_uint(v);
    u += 0x7fffu + ((u >> 16) & 1u);
    return (ushort_t)(u >> 16);
}
__device__ inline float bf16_to_f(ushort_t h) {
    return __uint_as_float((uint_t)h << 16);
}

// ---------------- combined bucket + prep ----------------

struct WPack {
    const float* srcp[5];
    ushort_t* dstp[5];
    int K[5], N[5], beg[5], end[5];
};

__global__ __launch_bounds__(1024)
void k_work(const int* __restrict__ src, const int* __restrict__ dst,
            uint_t* __restrict__ pairs, int* __restrict__ bcnt, int E, int nbk,
            int bbl, const float* __restrict__ x, ushort_t* __restrict__ xh,
            ushort_t* __restrict__ xl, int NS, WPack wp, int total) {
    int tid = threadIdx.x;
    if (blockIdx.x >= bbl) {
        int t = (blockIdx.x - bbl) * 1024 + tid;
        if (t < NS) {
            float v = x[t];
            ushort_t h = bf16_rne(v);
            xh[t] = h;
            xl[t] = bf16_rne(v - bf16_to_f(h));
            return;
        }
        t -= NS;
        if (t >= total) return;
#pragma unroll
        for (int m = 0; m < 5; ++m) {
            if (t >= wp.beg[m] && t < wp.end[m]) {
                int i = t - wp.beg[m];
                int K = wp.K[m], N = wp.N[m];
                int k = i / N, nn = i % N;
                int NT = N >> 4;
                int kt = k >> 5, bq = (k >> 3) & 3, j = k & 7;
                int nt = nn >> 4, lane = (bq << 4) | (nn & 15);
                int base = (((kt * NT + nt) << 6) + lane) * 8 + j;
                int halfsz = (K >> 5) * NT * 512;
                float v = wp.srcp[m][i];
                ushort_t h = bf16_rne(v);
                wp.dstp[m][base] = h;
                wp.dstp[m][halfsz + base] = bf16_rne(v - bf16_to_f(h));
            }
        }
        return;
    }

    __shared__ int h[4][512];
    int sub = tid & 3;
    for (int i = tid; i < 4 * 512; i += 1024) ((int*)h)[i] = 0;
    __syncthreads();

    int e = blockIdx.x * EPB + tid * 4;
    bool full = (e + 4 <= E);
    int4 d4 = {0, 0, 0, 0}, s4 = {0, 0, 0, 0};
    if (full) {
        d4 = *(const int4*)(dst + e);
        s4 = *(const int4*)(src + e);
        atomicAdd(&h[sub][d4.x >> BKT_SHIFT], 1);
        atomicAdd(&h[sub][d4.y >> BKT_SHIFT], 1);
        atomicAdd(&h[sub][d4.z >> BKT_SHIFT], 1);
        atomicAdd(&h[sub][d4.w >> BKT_SHIFT], 1);
    } else {
        for (int t = e; t < E && t < e + 4; ++t)
            atomicAdd(&h[sub][dst[t] >> BKT_SHIFT], 1);
    }
    __syncthreads();
    for (int i = tid; i < nbk; i += 1024) {
        int c0 = h[0][i], c1 = h[1][i], c2 = h[2][i], c3 = h[3][i];
        int c = c0 + c1 + c2 + c3;
        int bs = c ? atomicAdd(&bcnt[i], c) : 0;
        h[0][i] = bs; h[1][i] = bs + c0; h[2][i] = bs + c0 + c1;
        h[3][i] = bs + c0 + c1 + c2;
    }
    __syncthreads();
    if (full) {
        int dd[4] = {d4.x, d4.y, d4.z, d4.w};
        int ss[4] = {s4.x, s4.y, s4.z, s4.w};
#pragma unroll
        for (int t = 0; t < 4; ++t) {
            int b = dd[t] >> BKT_SHIFT;
            int r = atomicAdd(&h[sub][b], 1);
            pairs[(size_t)b * BKT_CAP + r] =
                (uint_t)(ss[t] & 0xFFFF) | ((uint_t)(dd[t] & (BKT_NODES - 1)) << 16);
        }
    } else {
        for (int t = e; t < E && t < e + 4; ++t) {
            int d = dst[t];
            int b = d >> BKT_SHIFT;
            int r = atomicAdd(&h[sub][b], 1);
            pairs[(size_t)b * BKT_CAP + r] =
                (uint_t)(src[t] & 0xFFFF) | ((uint_t)(d & (BKT_NODES - 1)) << 16);
        }
    }
}

// ---------------- per-bucket CSR finalize ----------------

__global__ __launch_bounds__(1024) void k_csr(const uint_t* __restrict__ pairs,
                                              const int* __restrict__ bcnt,
                                              int* __restrict__ off,
                                              ushort_t* __restrict__ col, int n) {
    __shared__ int hist[BKT_NODES];
    __shared__ int s[BKT_NODES];
    __shared__ int cur[BKT_NODES];
    __shared__ int bofs_s;
    int b = blockIdx.x, tid = threadIdx.x;
    if (tid < 64) {
        int p = 0;
        for (int i = tid; i < b; i += 64) p += bcnt[i];
#pragma unroll
        for (int m = 1; m < 64; m <<= 1) p += __shfl_xor(p, m);
        if (tid == 0) bofs_s = p;
    }
    if (tid < BKT_NODES) hist[tid] = 0;
    __syncthreads();
    int bofs = bofs_s;
    int cnt = bcnt[b];
    const uint_t* p = pairs + (size_t)b * BKT_CAP;
    for (int i = tid; i < cnt; i += 1024) atomicAdd(&hist[(p[i] >> 16) & 127], 1);
    __syncthreads();
    int v = (tid < BKT_NODES) ? hist[tid] : 0;
    if (tid < BKT_NODES) s[tid] = v;
    __syncthreads();
    for (int ofs = 1; ofs < BKT_NODES; ofs <<= 1) {
        int t = (tid >= ofs && tid < BKT_NODES) ? s[tid - ofs] : 0;
        __syncthreads();
        if (tid < BKT_NODES) s[tid] += t;
        __syncthreads();
    }
    if (tid < BKT_NODES) {
        int excl = bofs + s[tid] - v;
        int node = b * BKT_NODES + tid;
        if (node <= n) off[node] = excl;
        cur[tid] = excl;
    }
    __syncthreads();
    for (int i = tid; i < cnt; i += 1024) {
        uint_t pk = p[i];
        int pos = atomicAdd(&cur[(pk >> 16) & 127], 1);
        col[pos] = (ushort_t)(pk & 0xFFFF);
    }
}

// ---------------- aggregation cores ----------------

__device__ inline void accum2m(float2 (&a)[4], uint4 q, float m) {
    const uint_t* u = (const uint_t*)&q;
#pragma unroll
    for (int i = 0; i < 4; ++i) {
        a[i].x = fmaf(m, __uint_as_float(u[i] << 16), a[i].x);
        a[i].y = fmaf(m, __uint_as_float(u[i] & 0xffff0000u), a[i].y);
    }
}

// u8 gather (layer-2): row = 128 x 1B = 1 cache line (vs 2 for bf16).
__global__ __launch_bounds__(256)
void k_agg_u8(const uchar_t* __restrict__ fq, const int* __restrict__ off,
              const ushort_t* __restrict__ col,
              ushort_t* __restrict__ ah, ushort_t* __restrict__ al, int n) {
    constexpr int EPI = 8;
    int wave = (int)((blockIdx.x * (unsigned)blockDim.x + threadIdx.x) >> 6);
    int lane = threadIdx.x & 63;
    if (wave >= n) return;
    int li = lane & 7;
    int sub = lane >> 3;
    int s0 = off[wave], s1 = off[wave + 1];
    const uchar_t* fbase = fq + li * 16;

    uint_t ae[4] = {0, 0, 0, 0}, ao[4] = {0, 0, 0, 0};
    int e = s0;
    for (; e + 4 * EPI <= s1; e += 4 * EPI) {
        int c[4];
        uint4 q[4];
#pragma unroll
        for (int j = 0; j < 4; ++j) c[j] = col[e + j * EPI + sub];
#pragma unroll
        for (int j = 0; j < 4; ++j) q[j] = *(const uint4*)(fbase + (size_t)c[j] * 128);
#pragma unroll
        for (int j = 0; j < 4; ++j) {
            const uint_t* u = (const uint_t*)&q[j];
#pragma unroll
            for (int i = 0; i < 4; ++i) {
                ae[i] += u[i] & 0x00FF00FFu;
                ao[i] += (u[i] >> 8) & 0x00FF00FFu;
            }
        }
    }
    if (e < s1) {
        int last = s1 - 1;
        int idx[4];
        uint_t msk[4];
        int c[4];
        uint4 q[4];
#pragma unroll
        for (int j = 0; j < 4; ++j) {
            idx[j] = e + j * EPI + sub;
            msk[j] = (idx[j] < s1) ? 0xFFFFFFFFu : 0u;
            c[j] = col[min(idx[j], last)];
        }
#pragma unroll
        for (int j = 0; j < 4; ++j) q[j] = *(const uint4*)(fbase + (size_t)c[j] * 128);
#pragma unroll
        for (int j = 0; j < 4; ++j) {
            const uint_t* u = (const uint_t*)&q[j];
#pragma unroll
            for (int i = 0; i < 4; ++i) {
                uint_t um = u[i] & msk[j];
                ae[i] += um & 0x00FF00FFu;
                ao[i] += (um >> 8) & 0x00FF00FFu;
            }
        }
    }
#pragma unroll
    for (int m = 8; m < 64; m <<= 1) {
#pragma unroll
        for (int i = 0; i < 4; ++i) {
            ae[i] += __shfl_xor(ae[i], m);
            ao[i] += __shfl_xor(ao[i], m);
        }
    }
    if (sub == 0) {
        float inv = QINV / fmaxf((float)(s1 - s0), 1.f);
        ushort_t vh[16], vl[16];
#pragma unroll
        for (int i = 0; i < 4; ++i) {
            uint_t f[4] = {ae[i] & 0xFFFFu, ao[i] & 0xFFFFu,
                           ae[i] >> 16, ao[i] >> 16};
#pragma unroll
            for (int b = 0; b < 4; ++b) {
                float mval = (float)f[b] * inv;
                ushort_t h = bf16_rne(mval);
                vh[i * 4 + b] = h;
                vl[i * 4 + b] = bf16_rne(mval - bf16_to_f(h));
            }
        }
        size_t o = (size_t)wave * 128 + li * 16;
        *(ushort8*)(ah + o) = *(ushort8*)&vh[0];
        *(ushort8*)(ah + o + 8) = *(ushort8*)&vh[8];
        *(ushort8*)(al + o) = *(ushort8*)&vl[0];
        *(ushort8*)(al + o + 8) = *(ushort8*)&vl[8];
    }
}

__device__ inline f32x4 mfma3(f32x4 acc, short8 ah, short8 al, short8 bh, short8 bl) {
    acc = __builtin_amdgcn_mfma_f32_16x16x32_bf16(ah, bh, acc, 0, 0, 0);
    acc = __builtin_amdgcn_mfma_f32_16x16x32_bf16(al, bh, acc, 0, 0, 0);
    acc = __builtin_amdgcn_mfma_f32_16x16x32_bf16(ah, bl, acc, 0, 0, 0);
    return acc;
}

template <int DIN, int DOUT, int M2>
__device__ inline void mfma_pass(const ushort_t* __restrict__ Fh,
                                 const ushort_t* __restrict__ Fl,
                                 const ushort_t* __restrict__ Wp,
                                 f32x4 (&acc)[M2][DOUT / 16],
                                 int base, int n, int lane) {
    constexpr int KT = DIN / 32, NT = DOUT / 16;
    int col = lane & 15, quad = lane >> 4;
    short8 fh[M2][KT], fl[M2][KT];
#pragma unroll
    for (int c = 0; c < M2; ++c) {
        int row = base + c * 16 + col;
        if (row >= n) row = n - 1;
        size_t roff = (size_t)row * DIN + quad * 8;
#pragma unroll
        for (int kt = 0; kt < KT; ++kt) {
            fh[c][kt] = *(const short8*)(Fh + roff + kt * 32);
            fl[c][kt] = *(const short8*)(Fl + roff + kt * 32);
        }
    }
#pragma unroll
    for (int nt = 0; nt < NT; ++nt) {
#pragma unroll
        for (int kt = 0; kt < KT; ++kt) {
            const ushort_t* p = Wp + ((size_t)((kt * NT + nt) << 6) + lane) * 8;
            short8 bh = *(const short8*)p;
            short8 bl = *(const short8*)(p + (size_t)KT * NT * 512);
#pragma unroll
            for (int c = 0; c < M2; ++c)
                acc[c][nt] = mfma3(acc[c][nt], fh[c][kt], fl[c][kt], bh, bl);
        }
    }
}

// ---------------- layer 1 fused: bf16-agg64 (interleaved) + dense1 ----------
// Wave owns 4 nodes; their gathers are interleaved in one loop (4 independent
// loads in flight every iteration, ONE shfl/LDS drain at the end instead of 4).
// Per-slot accumulation order is identical to the old chunked loop.

__global__ __launch_bounds__(512)
void k_layer1(const ushort_t* __restrict__ xh, const ushort_t* __restrict__ xl,
              const int* __restrict__ off, const ushort_t* __restrict__ col,
              const ushort_t* __restrict__ Wlp, const ushort_t* __restrict__ Wrp,
              const float* __restrict__ bias, ushort_t* __restrict__ Oh,
              ushort_t* __restrict__ Ol, uchar_t* __restrict__ Oq, int n) {
    constexpr int LPR = 8, EPI = 8;
    __shared__ ushort_t Ahs[32][72];
    __shared__ ushort_t Als[32][72];
    int tid = threadIdx.x, waveid = tid >> 6, lane = tid & 63;
    int base = blockIdx.x * 32;
    int li = lane & (LPR - 1);
    int sub = lane / LPR;

    // ---- interleaved agg: 4 nodes, one loop ----
    int nodebase = base + waveid * 4;
    int s0q[4], s1q[4];
#pragma unroll
    for (int q = 0; q < 4; ++q) {
        int nd = nodebase + q; if (nd >= n) nd = n - 1;
        s0q[q] = off[nd]; s1q[q] = off[nd + 1];
    }
    float2 a2[4][4];
#pragma unroll
    for (int q = 0; q < 4; ++q)
#pragma unroll
        for (int j = 0; j < 4; ++j) a2[q][j] = (float2){0.f, 0.f};
    int iters = 0;
#pragma unroll
    for (int q = 0; q < 4; ++q) {
        int it = (s1q[q] - s0q[q] + EPI - 1) >> 3;
        iters = max(iters, it);
    }
    const ushort_t* fb = xh + li * 8;
    for (int it = 0; it < iters; ++it) {
        int cc[4];
        float mm[4];
#pragma unroll
        for (int q = 0; q < 4; ++q) {
            int iq = s0q[q] + it * EPI + sub;
            mm[q] = (iq < s1q[q]) ? 1.f : 0.f;
            int idx = iq < s1q[q] ? iq : s1q[q] - 1;
            if (idx < 0) idx = 0;           // deg==0 guard
            cc[q] = col[idx];
        }
        uint4 qd[4];
#pragma unroll
        for (int q = 0; q < 4; ++q)
            qd[q] = *(const uint4*)(fb + (size_t)cc[q] * 64);
#pragma unroll
        for (int q = 0; q < 4; ++q) accum2m(a2[q], qd[q], mm[q]);
    }
    // one drain: butterfly + pack + LDS store per node
#pragma unroll
    for (int q = 0; q < 4; ++q) {
#pragma unroll
        for (int m = LPR; m < 64; m <<= 1) {
#pragma unroll
            for (int j = 0; j < 4; ++j) {
                a2[q][j].x += __shfl_xor(a2[q][j].x, m);
                a2[q][j].y += __shfl_xor(a2[q][j].y, m);
            }
        }
        if (sub == 0) {
            float inv = 1.f / fmaxf((float)(s1q[q] - s0q[q]), 1.f);
            ushort8 vh, vl;
#pragma unroll
            for (int j = 0; j < 4; ++j) {
                float mx = a2[q][j].x * inv, my = a2[q][j].y * inv;
                ushort_t hx = bf16_rne(mx), hy = bf16_rne(my);
                vh[2 * j] = hx;     vl[2 * j] = bf16_rne(mx - bf16_to_f(hx));
                vh[2 * j + 1] = hy; vl[2 * j + 1] = bf16_rne(my - bf16_to_f(hy));
            }
            *(ushort8*)&Ahs[waveid * 4 + q][li * 8] = vh;
            *(ushort8*)&Als[waveid * 4 + q][li * 8] = vl;
        }
    }
    __syncthreads();

    // ---- dense: 32x128 = 2 row-tiles x 8 col-tiles ----
    int rowt = waveid >> 2, c0 = waveid & 3;
    int colq = lane & 15, quad = lane >> 4;
    int arow = rowt * 16 + colq;
    short8 fah[2], fal[2], fxh[2], fxl[2];
#pragma unroll
    for (int kt = 0; kt < 2; ++kt) {
        fah[kt] = *(const short8*)&Ahs[arow][kt * 32 + quad * 8];
        fal[kt] = *(const short8*)&Als[arow][kt * 32 + quad * 8];
    }
    int grow = base + arow; if (grow >= n) grow = n - 1;
#pragma unroll
    for (int kt = 0; kt < 2; ++kt) {
        fxh[kt] = *(const short8*)(xh + (size_t)grow * 64 + kt * 32 + quad * 8);
        fxl[kt] = *(const short8*)(xl + (size_t)grow * 64 + kt * 32 + quad * 8);
    }
#pragma unroll
    for (int t = 0; t < 2; ++t) {
        int nt = c0 + t * 4;
        float bv = bias[nt * 16 + colq];
        f32x4 acc = (f32x4){bv, bv, bv, bv};
#pragma unroll
        for (int kt = 0; kt < 2; ++kt) {
            const ushort_t* pL = Wlp + ((size_t)((kt * 8 + nt) << 6) + lane) * 8;
            acc = mfma3(acc, fah[kt], fal[kt],
                        *(const short8*)pL, *(const short8*)(pL + 8192));
            const ushort_t* pR = Wrp + ((size_t)((kt * 8 + nt) << 6) + lane) * 8;
            acc = mfma3(acc, fxh[kt], fxl[kt],
                        *(const short8*)pR, *(const short8*)(pR + 8192));
        }
        int rowb = base + rowt * 16 + quad * 4;
        int cix = nt * 16 + colq;
#pragma unroll
        for (int r = 0; r < 4; ++r) {
            int row = rowb + r;
            if (row < n) {
                float v = fmaxf(acc[r], 0.f);
                ushort_t h = bf16_rne(v);
                Oh[(size_t)row * 128 + cix] = h;
                Ol[(size_t)row * 128 + cix] = bf16_rne(v - bf16_to_f(h));
                int qv = (int)(v * QSCALE + 0.5f);
                Oq[(size_t)row * 128 + cix] = (uchar_t)(qv > 255 ? 255 : qv);
            }
        }
    }
}

// ---------------- dense2 + out fused (h2 in LDS only) ----------------

#define LROW 136
__global__ __launch_bounds__(256)
void k_dense23(const ushort_t* __restrict__ Ah, const ushort_t* __restrict__ Al,
               const ushort_t* __restrict__ Xh, const ushort_t* __restrict__ Xl,
               const ushort_t* __restrict__ Wlp, const ushort_t* __restrict__ Wrp,
               const float* __restrict__ b2, const ushort_t* __restrict__ Wop,
               const float* __restrict__ bo, float* __restrict__ out, int n) {
    constexpr int DIN = 128, DOUT = 128, NT = DOUT / 16;
    __shared__ ushort_t lds[4][2][16 * LROW];
    int waveid = threadIdx.x >> 6;
    int lane = threadIdx.x & 63;
    int wave = (blockIdx.x * blockDim.x + threadIdx.x) >> 6;
    int nw = (n + 15) / 16;
    if (wave >= nw) wave = nw - 1;
    int base = wave * 16;
    int col = lane & 15, quad = lane >> 4;

    f32x4 acc[1][NT];
#pragma unroll
    for (int nt = 0; nt < NT; ++nt) {
        float bv = b2[nt * 16 + col];
        acc[0][nt] = (f32x4){bv, bv, bv, bv};
    }
    mfma_pass<DIN, DOUT, 1>(Ah, Al, Wlp, acc, base, n, lane);
    mfma_pass<DIN, DOUT, 1>(Xh, Xl, Wrp, acc, base, n, lane);

    ushort_t* Lh = &lds[waveid][0][0];
    ushort_t* Ll = &lds[waveid][1][0];
#pragma unroll
    for (int nt = 0; nt < NT; ++nt) {
        int cix = nt * 16 + col;
#pragma unroll
        for (int r = 0; r < 4; ++r) {
            int row = quad * 4 + r;
            float v = fmaxf(acc[0][nt][r], 0.f);
            ushort_t h = bf16_rne(v);
            Lh[row * LROW + cix] = h;
            Ll[row * LROW + cix] = bf16_rne(v - bf16_to_f(h));
        }
    }
    __syncthreads();

    constexpr int KT2 = 4, NT2 = 4;
    short8 ah[KT2], al[KT2];
    int arow = lane & 15;
#pragma unroll
    for (int kt = 0; kt < KT2; ++kt) {
        ah[kt] = *(const short8*)(Lh + arow * LROW + kt * 32 + quad * 8);
        al[kt] = *(const short8*)(Ll + arow * LROW + kt * 32 + quad * 8);
    }
    f32x4 acc2[NT2];
#pragma unroll
    for (int nt = 0; nt < NT2; ++nt) {
        float bv = bo[nt * 16 + col];
        acc2[nt] = (f32x4){bv, bv, bv, bv};
    }
#pragma unroll
    for (int nt = 0; nt < NT2; ++nt) {
#pragma unroll
        for (int kt = 0; kt < KT2; ++kt) {
            const ushort_t* p = Wop + ((size_t)((kt * 4 + nt) << 6) + lane) * 8;
            acc2[nt] = mfma3(acc2[nt], ah[kt], al[kt],
                             *(const short8*)p, *(const short8*)(p + 8192));
        }
    }
    int rowb = base + quad * 4;
#pragma unroll
    for (int nt = 0; nt < NT2; ++nt) {
        int cix = nt * 16 + col;
#pragma unroll
        for (int r = 0; r < 4; ++r) {
            int row = rowb + r;
            if (row < n) out[(size_t)row * 64 + cix] = acc2[nt][r];
        }
    }
}

// ---------------- launch ----------------

static inline size_t align256(size_t x) { return (x + 255) & ~(size_t)255; }

extern "C" void kernel_launch(void* const* d_in, const int* in_sizes, int n_in,
                              void* d_out, int out_size, void* d_ws, size_t ws_size,
                              hipStream_t stream) {
    const float* x   = (const float*)d_in[0];
    const int*   ei  = (const int*)d_in[1];
    const float* Wl1 = (const float*)d_in[2];
    const float* bl1 = (const float*)d_in[3];
    const float* Wr1 = (const float*)d_in[4];
    const float* Wl2 = (const float*)d_in[5];
    const float* bl2 = (const float*)d_in[6];
    const float* Wr2 = (const float*)d_in[7];
    const float* Wo  = (const float*)d_in[8];
    const float* bo  = (const float*)d_in[9];

    const int N = in_sizes[0] / 64;   // 50000
    const int E = in_sizes[1] / 2;    // 1600000
    const int* src = ei;
    const int* dst = ei + E;
    const int nbk = (N + BKT_NODES - 1) >> BKT_SHIFT;   // 391

    char* ws = (char*)d_ws;
    int* off = (int*)ws;            ws += align256((size_t)(N + 1) * 4);
    int* bcnt = (int*)ws;           ws += align256((size_t)nbk * 4);
    uint_t* pairs = (uint_t*)ws;    ws += align256((size_t)nbk * BKT_CAP * 4);
    ushort_t* col = (ushort_t*)ws;  ws += align256((size_t)E * 2);
    ushort_t* xh  = (ushort_t*)ws;  ws += align256((size_t)N * 64 * 2);
    ushort_t* xl  = (ushort_t*)ws;  ws += align256((size_t)N * 64 * 2);
    ushort_t* h1h = (ushort_t*)ws;  ws += align256((size_t)N * 128 * 2);
    ushort_t* h1l = (ushort_t*)ws;  ws += align256((size_t)N * 128 * 2);
    uchar_t*  h1q = (uchar_t*)ws;   ws += align256((size_t)N * 128);
    ushort_t* a2h = (ushort_t*)ws;  ws += align256((size_t)N * 128 * 2);
    ushort_t* a2l = (ushort_t*)ws;  ws += align256((size_t)N * 128 * 2);
    ushort_t* Wl1p = (ushort_t*)ws; ws += align256((size_t)2 * 64 * 128 * 2);
    ushort_t* Wr1p = (ushort_t*)ws; ws += align256((size_t)2 * 64 * 128 * 2);
    ushort_t* Wl2p = (ushort_t*)ws; ws += align256((size_t)2 * 128 * 128 * 2);
    ushort_t* Wr2p = (ushort_t*)ws; ws += align256((size_t)2 * 128 * 128 * 2);
    ushort_t* Wop  = (ushort_t*)ws; ws += align256((size_t)2 * 128 * 64 * 2);

    WPack wp;
    wp.srcp[0] = Wl1; wp.dstp[0] = Wl1p; wp.K[0] = 64;  wp.N[0] = 128;
    wp.srcp[1] = Wr1; wp.dstp[1] = Wr1p; wp.K[1] = 64;  wp.N[1] = 128;
    wp.srcp[2] = Wl2; wp.dstp[2] = Wl2p; wp.K[2] = 128; wp.N[2] = 128;
    wp.srcp[3] = Wr2; wp.dstp[3] = Wr2p; wp.K[3] = 128; wp.N[3] = 128;
    wp.srcp[4] = Wo;  wp.dstp[4] = Wop;  wp.K[4] = 128; wp.N[4] = 64;
    int acc_el = 0;
    for (int m = 0; m < 5; ++m) {
        wp.beg[m] = acc_el; acc_el += wp.K[m] * wp.N[m]; wp.end[m] = acc_el;
    }
    int NS = N * 64;

    // 1. zero bcnt + combined bucket/prep launch
    hipMemsetAsync(bcnt, 0, (size_t)nbk * 4, stream);
    int bbl = (E + EPB - 1) / EPB;
    int pbl = (NS + acc_el + 1023) / 1024;
    k_work<<<bbl + pbl, 1024, 0, stream>>>(src, dst, pairs, bcnt, E, nbk, bbl,
                                           x, xh, xl, NS, wp, acc_el);

    // 2. CSR finalize
    k_csr<<<nbk, 1024, 0, stream>>>(pairs, bcnt, off, col, N);

    // 3. layer 1 fused (interleaved bf16 agg64 + dense1, emits h1 pair + u8)
    k_layer1<<<(N + 31) / 32, 512, 0, stream>>>(xh, xl, off, col, Wl1p, Wr1p,
                                                bl1, h1h, h1l, h1q, N);

    // 4. layer 2 aggregation from u8 h1 (1 line/row)
    int aggbl = (N * 64 + 255) / 256;
    k_agg_u8<<<aggbl, 256, 0, stream>>>(h1q, off, col, a2h, a2l, N);

    // 5. dense2 + out fused
    int dbl2 = ((N + 15) / 16 + 3) / 4;
    k_dense23<<<dbl2, 256, 0, stream>>>(a2h, a2l, h1h, h1l, Wl2p, Wr2p, bl2,
                                        Wop, bo, (float*)d_out, N);
}

// Round 16
// 229.022 us; speedup vs baseline: 1.0175x; 1.0175x over previous
//
#include <hip/hip_runtime.h>

// GraphSAGE encoder on MI355X — pipeline (r12-proven best, ~228us):
//   memset(bcnt) ; k_work (bucket + prep in one launch) ; k_csr
//   k_layer1 (bf16-agg64 + dense1 fused; chunked 4-deep gathers, 4 nodes/wave)
//   k_agg_u8 (layer-2 aggregation from u8 h1: 1 line/row — the r12 win)
//   k_dense23 (dense2+out fused, h2 in LDS; self-terms read full-prec pairs)
// Session laws (measured r4-r15):
//  - u8 quant pays only when it halves LINE REQUESTS, not bytes (r12 vs r13).
//  - agg must not share fine-grained block barriers with dense (r9).
//  - interleaving multi-node gathers loses to chunked loops: +VGPR cost and
//    4*max(deg) masked iterations vs sum(deg) (r15).
// Dense: split-bf16 MFMA (A@B ~= Ah@Bh + Al@Bh + Ah@Bl, fp32-equivalent).

typedef unsigned short ushort_t;
typedef unsigned int uint_t;
typedef unsigned char uchar_t;
typedef __attribute__((ext_vector_type(8))) short short8;
typedef __attribute__((ext_vector_type(8))) ushort_t ushort8;
typedef __attribute__((ext_vector_type(4))) float f32x4;

#define BKT_SHIFT 7
#define BKT_NODES 128
#define BKT_CAP   5120
#define EPB       4096
#define QSCALE    32.0f          // h1q = round(h1 * 32), u8 (post-relu >= 0)
#define QINV      0.03125f

__device__ inline ushort_t bf16_rne(float v) {
    uint_t u = __float_as_uint(v);
    u += 0x7fffu + ((u >> 16) & 1u);
    return (ushort_t)(u >> 16);
}
__device__ inline float bf16_to_f(ushort_t h) {
    return __uint_as_float((uint_t)h << 16);
}

// ---------------- combined bucket + prep ----------------

struct WPack {
    const float* srcp[5];
    ushort_t* dstp[5];
    int K[5], N[5], beg[5], end[5];
};

__global__ __launch_bounds__(1024)
void k_work(const int* __restrict__ src, const int* __restrict__ dst,
            uint_t* __restrict__ pairs, int* __restrict__ bcnt, int E, int nbk,
            int bbl, const float* __restrict__ x, ushort_t* __restrict__ xh,
            ushort_t* __restrict__ xl, int NS, WPack wp, int total) {
    int tid = threadIdx.x;
    if (blockIdx.x >= bbl) {
        int t = (blockIdx.x - bbl) * 1024 + tid;
        if (t < NS) {
            float v = x[t];
            ushort_t h = bf16_rne(v);
            xh[t] = h;
            xl[t] = bf16_rne(v - bf16_to_f(h));
            return;
        }
        t -= NS;
        if (t >= total) return;
#pragma unroll
        for (int m = 0; m < 5; ++m) {
            if (t >= wp.beg[m] && t < wp.end[m]) {
                int i = t - wp.beg[m];
                int K = wp.K[m], N = wp.N[m];
                int k = i / N, nn = i % N;
                int NT = N >> 4;
                int kt = k >> 5, bq = (k >> 3) & 3, j = k & 7;
                int nt = nn >> 4, lane = (bq << 4) | (nn & 15);
                int base = (((kt * NT + nt) << 6) + lane) * 8 + j;
                int halfsz = (K >> 5) * NT * 512;
                float v = wp.srcp[m][i];
                ushort_t h = bf16_rne(v);
                wp.dstp[m][base] = h;
                wp.dstp[m][halfsz + base] = bf16_rne(v - bf16_to_f(h));
            }
        }
        return;
    }

    __shared__ int h[4][512];
    int sub = tid & 3;
    for (int i = tid; i < 4 * 512; i += 1024) ((int*)h)[i] = 0;
    __syncthreads();

    int e = blockIdx.x * EPB + tid * 4;
    bool full = (e + 4 <= E);
    int4 d4 = {0, 0, 0, 0}, s4 = {0, 0, 0, 0};
    if (full) {
        d4 = *(const int4*)(dst + e);
        s4 = *(const int4*)(src + e);
        atomicAdd(&h[sub][d4.x >> BKT_SHIFT], 1);
        atomicAdd(&h[sub][d4.y >> BKT_SHIFT], 1);
        atomicAdd(&h[sub][d4.z >> BKT_SHIFT], 1);
        atomicAdd(&h[sub][d4.w >> BKT_SHIFT], 1);
    } else {
        for (int t = e; t < E && t < e + 4; ++t)
            atomicAdd(&h[sub][dst[t] >> BKT_SHIFT], 1);
    }
    __syncthreads();
    for (int i = tid; i < nbk; i += 1024) {
        int c0 = h[0][i], c1 = h[1][i], c2 = h[2][i], c3 = h[3][i];
        int c = c0 + c1 + c2 + c3;
        int bs = c ? atomicAdd(&bcnt[i], c) : 0;
        h[0][i] = bs; h[1][i] = bs + c0; h[2][i] = bs + c0 + c1;
        h[3][i] = bs + c0 + c1 + c2;
    }
    __syncthreads();
    if (full) {
        int dd[4] = {d4.x, d4.y, d4.z, d4.w};
        int ss[4] = {s4.x, s4.y, s4.z, s4.w};
#pragma unroll
        for (int t = 0; t < 4; ++t) {
            int b = dd[t] >> BKT_SHIFT;
            int r = atomicAdd(&h[sub][b], 1);
            pairs[(size_t)b * BKT_CAP + r] =
                (uint_t)(ss[t] & 0xFFFF) | ((uint_t)(dd[t] & (BKT_NODES - 1)) << 16);
        }
    } else {
        for (int t = e; t < E && t < e + 4; ++t) {
            int d = dst[t];
            int b = d >> BKT_SHIFT;
            int r = atomicAdd(&h[sub][b], 1);
            pairs[(size_t)b * BKT_CAP + r] =
                (uint_t)(src[t] & 0xFFFF) | ((uint_t)(d & (BKT_NODES - 1)) << 16);
        }
    }
}

// ---------------- per-bucket CSR finalize ----------------

__global__ __launch_bounds__(1024) void k_csr(const uint_t* __restrict__ pairs,
                                              const int* __restrict__ bcnt,
                                              int* __restrict__ off,
                                              ushort_t* __restrict__ col, int n) {
    __shared__ int hist[BKT_NODES];
    __shared__ int s[BKT_NODES];
    __shared__ int cur[BKT_NODES];
    __shared__ int bofs_s;
    int b = blockIdx.x, tid = threadIdx.x;
    if (tid < 64) {
        int p = 0;
        for (int i = tid; i < b; i += 64) p += bcnt[i];
#pragma unroll
        for (int m = 1; m < 64; m <<= 1) p += __shfl_xor(p, m);
        if (tid == 0) bofs_s = p;
    }
    if (tid < BKT_NODES) hist[tid] = 0;
    __syncthreads();
    int bofs = bofs_s;
    int cnt = bcnt[b];
    const uint_t* p = pairs + (size_t)b * BKT_CAP;
    for (int i = tid; i < cnt; i += 1024) atomicAdd(&hist[(p[i] >> 16) & 127], 1);
    __syncthreads();
    int v = (tid < BKT_NODES) ? hist[tid] : 0;
    if (tid < BKT_NODES) s[tid] = v;
    __syncthreads();
    for (int ofs = 1; ofs < BKT_NODES; ofs <<= 1) {
        int t = (tid >= ofs && tid < BKT_NODES) ? s[tid - ofs] : 0;
        __syncthreads();
        if (tid < BKT_NODES) s[tid] += t;
        __syncthreads();
    }
    if (tid < BKT_NODES) {
        int excl = bofs + s[tid] - v;
        int node = b * BKT_NODES + tid;
        if (node <= n) off[node] = excl;
        cur[tid] = excl;
    }
    __syncthreads();
    for (int i = tid; i < cnt; i += 1024) {
        uint_t pk = p[i];
        int pos = atomicAdd(&cur[(pk >> 16) & 127], 1);
        col[pos] = (ushort_t)(pk & 0xFFFF);
    }
}

// ---------------- aggregation cores ----------------

__device__ inline void accum2(float2 (&a)[4], uint4 q) {
    const uint_t* u = (const uint_t*)&q;
#pragma unroll
    for (int i = 0; i < 4; ++i) {
        a[i].x += __uint_as_float(u[i] << 16);
        a[i].y += __uint_as_float(u[i] & 0xffff0000u);
    }
}
__device__ inline void accum2m(float2 (&a)[4], uint4 q, float m) {
    const uint_t* u = (const uint_t*)&q;
#pragma unroll
    for (int i = 0; i < 4; ++i) {
        a[i].x = fmaf(m, __uint_as_float(u[i] << 16), a[i].x);
        a[i].y = fmaf(m, __uint_as_float(u[i] & 0xffff0000u), a[i].y);
    }
}

// bf16 gather (layer-1, DIN=64 -> 128B rows = already 1 line), 4-deep ILP
template <int DIN>
__device__ inline void agg_node(const ushort_t* __restrict__ fbase,
                                const ushort_t* __restrict__ col,
                                int s0, int s1, int sub, float2 (&a2)[4]) {
    constexpr int LPR = DIN / 8, EPI = 64 / LPR;
    constexpr int DEEP = (DIN == 128) ? 8 : 4;
#pragma unroll
    for (int j = 0; j < 4; ++j) a2[j] = (float2){0.f, 0.f};
    int e = s0;
    for (; e + DEEP * EPI <= s1; e += DEEP * EPI) {
        int c[DEEP];
        uint4 q[DEEP];
#pragma unroll
        for (int j = 0; j < DEEP; ++j) c[j] = col[e + j * EPI + sub];
#pragma unroll
        for (int j = 0; j < DEEP; ++j) q[j] = *(const uint4*)(fbase + (size_t)c[j] * DIN);
#pragma unroll
        for (int j = 0; j < DEEP; ++j) accum2(a2, q[j]);
    }
    for (; e < s1; e += 4 * EPI) {
        int last = s1 - 1;
        int i0 = e + sub, i1 = i0 + EPI, i2 = i1 + EPI, i3 = i2 + EPI;
        float m0 = (i0 < s1) ? 1.f : 0.f;
        float m1 = (i1 < s1) ? 1.f : 0.f;
        float m2 = (i2 < s1) ? 1.f : 0.f;
        float m3 = (i3 < s1) ? 1.f : 0.f;
        int c0 = col[min(i0, last)];
        int c1 = col[min(i1, last)];
        int c2 = col[min(i2, last)];
        int c3 = col[min(i3, last)];
        uint4 q0 = *(const uint4*)(fbase + (size_t)c0 * DIN);
        uint4 q1 = *(const uint4*)(fbase + (size_t)c1 * DIN);
        uint4 q2 = *(const uint4*)(fbase + (size_t)c2 * DIN);
        uint4 q3 = *(const uint4*)(fbase + (size_t)c3 * DIN);
        accum2m(a2, q0, m0); accum2m(a2, q1, m1);
        accum2m(a2, q2, m2); accum2m(a2, q3, m3);
    }
}

// u8 gather (layer-2): row = 128 x 1B = 1 cache line (vs 2 for bf16).
__global__ __launch_bounds__(256)
void k_agg_u8(const uchar_t* __restrict__ fq, const int* __restrict__ off,
              const ushort_t* __restrict__ col,
              ushort_t* __restrict__ ah, ushort_t* __restrict__ al, int n) {
    constexpr int EPI = 8;
    int wave = (int)((blockIdx.x * (unsigned)blockDim.x + threadIdx.x) >> 6);
    int lane = threadIdx.x & 63;
    if (wave >= n) return;
    int li = lane & 7;
    int sub = lane >> 3;
    int s0 = off[wave], s1 = off[wave + 1];
    const uchar_t* fbase = fq + li * 16;

    uint_t ae[4] = {0, 0, 0, 0}, ao[4] = {0, 0, 0, 0};
    int e = s0;
    for (; e + 4 * EPI <= s1; e += 4 * EPI) {
        int c[4];
        uint4 q[4];
#pragma unroll
        for (int j = 0; j < 4; ++j) c[j] = col[e + j * EPI + sub];
#pragma unroll
        for (int j = 0; j < 4; ++j) q[j] = *(const uint4*)(fbase + (size_t)c[j] * 128);
#pragma unroll
        for (int j = 0; j < 4; ++j) {
            const uint_t* u = (const uint_t*)&q[j];
#pragma unroll
            for (int i = 0; i < 4; ++i) {
                ae[i] += u[i] & 0x00FF00FFu;
                ao[i] += (u[i] >> 8) & 0x00FF00FFu;
            }
        }
    }
    if (e < s1) {
        int last = s1 - 1;
        int idx[4];
        uint_t msk[4];
        int c[4];
        uint4 q[4];
#pragma unroll
        for (int j = 0; j < 4; ++j) {
            idx[j] = e + j * EPI + sub;
            msk[j] = (idx[j] < s1) ? 0xFFFFFFFFu : 0u;
            c[j] = col[min(idx[j], last)];
        }
#pragma unroll
        for (int j = 0; j < 4; ++j) q[j] = *(const uint4*)(fbase + (size_t)c[j] * 128);
#pragma unroll
        for (int j = 0; j < 4; ++j) {
            const uint_t* u = (const uint_t*)&q[j];
#pragma unroll
            for (int i = 0; i < 4; ++i) {
                uint_t um = u[i] & msk[j];
                ae[i] += um & 0x00FF00FFu;
                ao[i] += (um >> 8) & 0x00FF00FFu;
            }
        }
    }
#pragma unroll
    for (int m = 8; m < 64; m <<= 1) {
#pragma unroll
        for (int i = 0; i < 4; ++i) {
            ae[i] += __shfl_xor(ae[i], m);
            ao[i] += __shfl_xor(ao[i], m);
        }
    }
    if (sub == 0) {
        float inv = QINV / fmaxf((float)(s1 - s0), 1.f);
        ushort_t vh[16], vl[16];
#pragma unroll
        for (int i = 0; i < 4; ++i) {
            uint_t f[4] = {ae[i] & 0xFFFFu, ao[i] & 0xFFFFu,
                           ae[i] >> 16, ao[i] >> 16};
#pragma unroll
            for (int b = 0; b < 4; ++b) {
                float mval = (float)f[b] * inv;
                ushort_t h = bf16_rne(mval);
                vh[i * 4 + b] = h;
                vl[i * 4 + b] = bf16_rne(mval - bf16_to_f(h));
            }
        }
        size_t o = (size_t)wave * 128 + li * 16;
        *(ushort8*)(ah + o) = *(ushort8*)&vh[0];
        *(ushort8*)(ah + o + 8) = *(ushort8*)&vh[8];
        *(ushort8*)(al + o) = *(ushort8*)&vl[0];
        *(ushort8*)(al + o + 8) = *(ushort8*)&vl[8];
    }
}

__device__ inline f32x4 mfma3(f32x4 acc, short8 ah, short8 al, short8 bh, short8 bl) {
    acc = __builtin_amdgcn_mfma_f32_16x16x32_bf16(ah, bh, acc, 0, 0, 0);
    acc = __builtin_amdgcn_mfma_f32_16x16x32_bf16(al, bh, acc, 0, 0, 0);
    acc = __builtin_amdgcn_mfma_f32_16x16x32_bf16(ah, bl, acc, 0, 0, 0);
    return acc;
}

template <int DIN, int DOUT, int M2>
__device__ inline void mfma_pass(const ushort_t* __restrict__ Fh,
                                 const ushort_t* __restrict__ Fl,
                                 const ushort_t* __restrict__ Wp,
                                 f32x4 (&acc)[M2][DOUT / 16],
                                 int base, int n, int lane) {
    constexpr int KT = DIN / 32, NT = DOUT / 16;
    int col = lane & 15, quad = lane >> 4;
    short8 fh[M2][KT], fl[M2][KT];
#pragma unroll
    for (int c = 0; c < M2; ++c) {
        int row = base + c * 16 + col;
        if (row >= n) row = n - 1;
        size_t roff = (size_t)row * DIN + quad * 8;
#pragma unroll
        for (int kt = 0; kt < KT; ++kt) {
            fh[c][kt] = *(const short8*)(Fh + roff + kt * 32);
            fl[c][kt] = *(const short8*)(Fl + roff + kt * 32);
        }
    }
#pragma unroll
    for (int nt = 0; nt < NT; ++nt) {
#pragma unroll
        for (int kt = 0; kt < KT; ++kt) {
            const ushort_t* p = Wp + ((size_t)((kt * NT + nt) << 6) + lane) * 8;
            short8 bh = *(const short8*)p;
            short8 bl = *(const short8*)(p + (size_t)KT * NT * 512);
#pragma unroll
            for (int c = 0; c < M2; ++c)
                acc[c][nt] = mfma3(acc[c][nt], fh[c][kt], fl[c][kt], bh, bl);
        }
    }
}

// ---------------- layer 1 fused: bf16-agg64 + dense1 (r12-proven) ----------

__global__ __launch_bounds__(512)
void k_layer1(const ushort_t* __restrict__ xh, const ushort_t* __restrict__ xl,
              const int* __restrict__ off, const ushort_t* __restrict__ col,
              const ushort_t* __restrict__ Wlp, const ushort_t* __restrict__ Wrp,
              const float* __restrict__ bias, ushort_t* __restrict__ Oh,
              ushort_t* __restrict__ Ol, uchar_t* __restrict__ Oq, int n) {
    constexpr int LPR = 8;
    __shared__ ushort_t Ahs[32][72];
    __shared__ ushort_t Als[32][72];
    int tid = threadIdx.x, waveid = tid >> 6, lane = tid & 63;
    int base = blockIdx.x * 32;
    int li = lane & (LPR - 1);
    int sub = lane / LPR;

    for (int q = 0; q < 4; ++q) {
        int node = base + waveid * 4 + q;
        int nd = node < n ? node : n - 1;
        int s0 = off[nd], s1 = off[nd + 1];
        float2 a2[4];
        agg_node<64>(xh + li * 8, col, s0, s1, sub, a2);
#pragma unroll
        for (int m = LPR; m < 64; m <<= 1) {
#pragma unroll
            for (int j = 0; j < 4; ++j) {
                a2[j].x += __shfl_xor(a2[j].x, m);
                a2[j].y += __shfl_xor(a2[j].y, m);
            }
        }
        if (sub == 0) {
            float inv = 1.f / fmaxf((float)(s1 - s0), 1.f);
            ushort8 vh, vl;
#pragma unroll
            for (int j = 0; j < 4; ++j) {
                float mx = a2[j].x * inv, my = a2[j].y * inv;
                ushort_t hx = bf16_rne(mx), hy = bf16_rne(my);
                vh[2 * j] = hx;     vl[2 * j] = bf16_rne(mx - bf16_to_f(hx));
                vh[2 * j + 1] = hy; vl[2 * j + 1] = bf16_rne(my - bf16_to_f(hy));
            }
            *(ushort8*)&Ahs[waveid * 4 + q][li * 8] = vh;
            *(ushort8*)&Als[waveid * 4 + q][li * 8] = vl;
        }
    }
    __syncthreads();

    int rowt = waveid >> 2, c0 = waveid & 3;
    int colq = lane & 15, quad = lane >> 4;
    int arow = rowt * 16 + colq;
    short8 fah[2], fal[2], fxh[2], fxl[2];
#pragma unroll
    for (int kt = 0; kt < 2; ++kt) {
        fah[kt] = *(const short8*)&Ahs[arow][kt * 32 + quad * 8];
        fal[kt] = *(const short8*)&Als[arow][kt * 32 + quad * 8];
    }
    int grow = base + arow; if (grow >= n) grow = n - 1;
#pragma unroll
    for (int kt = 0; kt < 2; ++kt) {
        fxh[kt] = *(const short8*)(xh + (size_t)grow * 64 + kt * 32 + quad * 8);
        fxl[kt] = *(const short8*)(xl + (size_t)grow * 64 + kt * 32 + quad * 8);
    }
#pragma unroll
    for (int t = 0; t < 2; ++t) {
        int nt = c0 + t * 4;
        float bv = bias[nt * 16 + colq];
        f32x4 acc = (f32x4){bv, bv, bv, bv};
#pragma unroll
        for (int kt = 0; kt < 2; ++kt) {
            const ushort_t* pL = Wlp + ((size_t)((kt * 8 + nt) << 6) + lane) * 8;
            acc = mfma3(acc, fah[kt], fal[kt],
                        *(const short8*)pL, *(const short8*)(pL + 8192));
            const ushort_t* pR = Wrp + ((size_t)((kt * 8 + nt) << 6) + lane) * 8;
            acc = mfma3(acc, fxh[kt], fxl[kt],
                        *(const short8*)pR, *(const short8*)(pR + 8192));
        }
        int rowb = base + rowt * 16 + quad * 4;
        int cix = nt * 16 + colq;
#pragma unroll
        for (int r = 0; r < 4; ++r) {
            int row = rowb + r;
            if (row < n) {
                float v = fmaxf(acc[r], 0.f);
                ushort_t h = bf16_rne(v);
                Oh[(size_t)row * 128 + cix] = h;
                Ol[(size_t)row * 128 + cix] = bf16_rne(v - bf16_to_f(h));
                int qv = (int)(v * QSCALE + 0.5f);
                Oq[(size_t)row * 128 + cix] = (uchar_t)(qv > 255 ? 255 : qv);
            }
        }
    }
}

// ---------------- dense2 + out fused (h2 in LDS only) ----------------

#define LROW 136
__global__ __launch_bounds__(256)
void k_dense23(const ushort_t* __restrict__ Ah, const ushort_t* __restrict__ Al,
               const ushort_t* __restrict__ Xh, const ushort_t* __restrict__ Xl,
               const ushort_t* __restrict__ Wlp, const ushort_t* __restrict__ Wrp,
               const float* __restrict__ b2, const ushort_t* __restrict__ Wop,
               const float* __restrict__ bo, float* __restrict__ out, int n) {
    constexpr int DIN = 128, DOUT = 128, NT = DOUT / 16;
    __shared__ ushort_t lds[4][2][16 * LROW];
    int waveid = threadIdx.x >> 6;
    int lane = threadIdx.x & 63;
    int wave = (blockIdx.x * blockDim.x + threadIdx.x) >> 6;
    int nw = (n + 15) / 16;
    if (wave >= nw) wave = nw - 1;
    int base = wave * 16;
    int col = lane & 15, quad = lane >> 4;

    f32x4 acc[1][NT];
#pragma unroll
    for (int nt = 0; nt < NT; ++nt) {
        float bv = b2[nt * 16 + col];
        acc[0][nt] = (f32x4){bv, bv, bv, bv};
    }
    mfma_pass<DIN, DOUT, 1>(Ah, Al, Wlp, acc, base, n, lane);
    mfma_pass<DIN, DOUT, 1>(Xh, Xl, Wrp, acc, base, n, lane);

    ushort_t* Lh = &lds[waveid][0][0];
    ushort_t* Ll = &lds[waveid][1][0];
#pragma unroll
    for (int nt = 0; nt < NT; ++nt) {
        int cix = nt * 16 + col;
#pragma unroll
        for (int r = 0; r < 4; ++r) {
            int row = quad * 4 + r;
            float v = fmaxf(acc[0][nt][r], 0.f);
            ushort_t h = bf16_rne(v);
            Lh[row * LROW + cix] = h;
            Ll[row * LROW + cix] = bf16_rne(v - bf16_to_f(h));
        }
    }
    __syncthreads();

    constexpr int KT2 = 4, NT2 = 4;
    short8 ah[KT2], al[KT2];
    int arow = lane & 15;
#pragma unroll
    for (int kt = 0; kt < KT2; ++kt) {
        ah[kt] = *(const short8*)(Lh + arow * LROW + kt * 32 + quad * 8);
        al[kt] = *(const short8*)(Ll + arow * LROW + kt * 32 + quad * 8);
    }
    f32x4 acc2[NT2];
#pragma unroll
    for (int nt = 0; nt < NT2; ++nt) {
        float bv = bo[nt * 16 + col];
        acc2[nt] = (f32x4){bv, bv, bv, bv};
    }
#pragma unroll
    for (int nt = 0; nt < NT2; ++nt) {
#pragma unroll
        for (int kt = 0; kt < KT2; ++kt) {
            const ushort_t* p = Wop + ((size_t)((kt * 4 + nt) << 6) + lane) * 8;
            acc2[nt] = mfma3(acc2[nt], ah[kt], al[kt],
                             *(const short8*)p, *(const short8*)(p + 8192));
        }
    }
    int rowb = base + quad * 4;
#pragma unroll
    for (int nt = 0; nt < NT2; ++nt) {
        int cix = nt * 16 + col;
#pragma unroll
        for (int r = 0; r < 4; ++r) {
            int row = rowb + r;
            if (row < n) out[(size_t)row * 64 + cix] = acc2[nt][r];
        }
    }
}

// ---------------- launch ----------------

static inline size_t align256(size_t x) { return (x + 255) & ~(size_t)255; }

extern "C" void kernel_launch(void* const* d_in, const int* in_sizes, int n_in,
                              void* d_out, int out_size, void* d_ws, size_t ws_size,
                              hipStream_t stream) {
    const float* x   = (const float*)d_in[0];
    const int*   ei  = (const int*)d_in[1];
    const float* Wl1 = (const float*)d_in[2];
    const float* bl1 = (const float*)d_in[3];
    const float* Wr1 = (const float*)d_in[4];
    const float* Wl2 = (const float*)d_in[5];
    const float* bl2 = (const float*)d_in[6];
    const float* Wr2 = (const float*)d_in[7];
    const float* Wo  = (const float*)d_in[8];
    const float* bo  = (const float*)d_in[9];

    const int N = in_sizes[0] / 64;   // 50000
    const int E = in_sizes[1] / 2;    // 1600000
    const int* src = ei;
    const int* dst = ei + E;
    const int nbk = (N + BKT_NODES - 1) >> BKT_SHIFT;   // 391

    char* ws = (char*)d_ws;
    int* off = (int*)ws;            ws += align256((size_t)(N + 1) * 4);
    int* bcnt = (int*)ws;           ws += align256((size_t)nbk * 4);
    uint_t* pairs = (uint_t*)ws;    ws += align256((size_t)nbk * BKT_CAP * 4);
    ushort_t* col = (ushort_t*)ws;  ws += align256((size_t)E * 2);
    ushort_t* xh  = (ushort_t*)ws;  ws += align256((size_t)N * 64 * 2);
    ushort_t* xl  = (ushort_t*)ws;  ws += align256((size_t)N * 64 * 2);
    ushort_t* h1h = (ushort_t*)ws;  ws += align256((size_t)N * 128 * 2);
    ushort_t* h1l = (ushort_t*)ws;  ws += align256((size_t)N * 128 * 2);
    uchar_t*  h1q = (uchar_t*)ws;   ws += align256((size_t)N * 128);
    ushort_t* a2h = (ushort_t*)ws;  ws += align256((size_t)N * 128 * 2);
    ushort_t* a2l = (ushort_t*)ws;  ws += align256((size_t)N * 128 * 2);
    ushort_t* Wl1p = (ushort_t*)ws; ws += align256((size_t)2 * 64 * 128 * 2);
    ushort_t* Wr1p = (ushort_t*)ws; ws += align256((size_t)2 * 64 * 128 * 2);
    ushort_t* Wl2p = (ushort_t*)ws; ws += align256((size_t)2 * 128 * 128 * 2);
    ushort_t* Wr2p = (ushort_t*)ws; ws += align256((size_t)2 * 128 * 128 * 2);
    ushort_t* Wop  = (ushort_t*)ws; ws += align256((size_t)2 * 128 * 64 * 2);

    WPack wp;
    wp.srcp[0] = Wl1; wp.dstp[0] = Wl1p; wp.K[0] = 64;  wp.N[0] = 128;
    wp.srcp[1] = Wr1; wp.dstp[1] = Wr1p; wp.K[1] = 64;  wp.N[1] = 128;
    wp.srcp[2] = Wl2; wp.dstp[2] = Wl2p; wp.K[2] = 128; wp.N[2] = 128;
    wp.srcp[3] = Wr2; wp.dstp[3] = Wr2p; wp.K[3] = 128; wp.N[3] = 128;
    wp.srcp[4] = Wo;  wp.dstp[4] = Wop;  wp.K[4] = 128; wp.N[4] = 64;
    int acc_el = 0;
    for (int m = 0; m < 5; ++m) {
        wp.beg[m] = acc_el; acc_el += wp.K[m] * wp.N[m]; wp.end[m] = acc_el;
    }
    int NS = N * 64;

    // 1. zero bcnt + combined bucket/prep launch
    hipMemsetAsync(bcnt, 0, (size_t)nbk * 4, stream);
    int bbl = (E + EPB - 1) / EPB;
    int pbl = (NS + acc_el + 1023) / 1024;
    k_work<<<bbl + pbl, 1024, 0, stream>>>(src, dst, pairs, bcnt, E, nbk, bbl,
                                           x, xh, xl, NS, wp, acc_el);

    // 2. CSR finalize
    k_csr<<<nbk, 1024, 0, stream>>>(pairs, bcnt, off, col, N);

    // 3. layer 1 fused (bf16 agg64 + dense1, emits h1 pair + u8)
    k_layer1<<<(N + 31) / 32, 512, 0, stream>>>(xh, xl, off, col, Wl1p, Wr1p,
                                                bl1, h1h, h1l, h1q, N);

    // 4. layer 2 aggregation from u8 h1 (1 line/row)
    int aggbl = (N * 64 + 255) / 256;
    k_agg_u8<<<aggbl, 256, 0, stream>>>(h1q, off, col, a2h, a2l, N);

    // 5. dense2 + out fused
    int dbl2 = ((N + 15) / 16 + 3) / 4;
    k_dense23<<<dbl2, 256, 0, stream>>>(a2h, a2l, h1h, h1l, Wl2p, Wr2p, bl2,
                                        Wop, bo, (float*)d_out, N);
}